// Round 5
// baseline (130.721 us; speedup 1.0000x reference)
//
#include <hip/hip_runtime.h>
#include <math.h>

#define BB 2
#define NN 384
#define DD 256
#define HH 8
#define RN (BB * NN)   // 768
#define INV_SQRT_HD 0.17677669529663687f   // 1/sqrt(32)
#define LOG2E 1.4426950408889634f
#define NLN2 -0.6931471805599453f
#define QSCALE (INV_SQRT_HD * LOG2E)

#define W2_ST 264   // bf16 stride, rb_w2 rows
#define EA_ST 392   // bf16 stride, e A-frag rows
#define T_ST  264   // f32 stride, T rows

typedef float f32x4 __attribute__((ext_vector_type(4)));
typedef __bf16 bf16x8 __attribute__((ext_vector_type(8)));
typedef __bf16 bf16x4 __attribute__((ext_vector_type(4)));

__device__ __forceinline__ f32x4 mfma16(bf16x8 a, bf16x8 b, f32x4 c) {
    return __builtin_amdgcn_mfma_f32_16x16x32_bf16(a, b, c, 0, 0, 0);
}

// d = av' - ap'  where primes are pre-scaled by log2e, i.e. d = -x*log2e.
// returns -log2e * silu(x); downstream folds: phase1 w2bf = -rb_w2 (since
// -ln2*log2e = -1 and scores want a log2e scale); phase2 Tl *= -ln2.
__device__ __forceinline__ float hidp(float d) {
    float e = __builtin_amdgcn_exp2f(d);              // = exp(-x)
    return d * __builtin_amdgcn_rcpf(1.0f + e);       // = -log2e * x * sigmoid(x)
}
__device__ __forceinline__ bf16x8 hid8(bf16x8 av, float4 a0, float4 a1) {
    bf16x8 r;
    r[0] = (__bf16)hidp((float)av[0] - a0.x);
    r[1] = (__bf16)hidp((float)av[1] - a0.y);
    r[2] = (__bf16)hidp((float)av[2] - a0.z);
    r[3] = (__bf16)hidp((float)av[3] - a0.w);
    r[4] = (__bf16)hidp((float)av[4] - a1.x);
    r[5] = (__bf16)hidp((float)av[5] - a1.y);
    r[6] = (__bf16)hidp((float)av[6] - a1.z);
    r[7] = (__bf16)hidp((float)av[7] - a1.w);
    return r;
}
__device__ __forceinline__ bf16x8 hid8s(bf16x8 av, float a) {
    bf16x8 r;
#pragma unroll
    for (int q = 0; q < 8; ++q) r[q] = (__bf16)hidp((float)av[q] - a);
    return r;
}
__device__ __forceinline__ bf16x8 pack8(float4 a, float4 b) {
    bf16x8 r;
    r[0] = (__bf16)a.x; r[1] = (__bf16)a.y; r[2] = (__bf16)a.z; r[3] = (__bf16)a.w;
    r[4] = (__bf16)b.x; r[5] = (__bf16)b.y; r[6] = (__bf16)b.z; r[7] = (__bf16)b.w;
    return r;
}

// ---------------- Kernel 1: fused prep ----------------
// blocks [0,576): qkv via MFMA.  blocks [576,1344): A-array precompute.
// q: f32 [768][256] pre-scaled by log2e/sqrt(32); k: bf16 [768][256];
// vT: bf16 [b][256(hd)][384(n)]
// Arb[r][c] = (coords_r . rb_w1_c)*log2e   (bf16, [768][256])
// ArvT[c][r] = (coords_r . rv_w1_c)*log2e  (bf16, [256][768])
__global__ __launch_bounds__(256) void prep_kernel(
    const float* __restrict__ x, const float* __restrict__ coords,
    const float* __restrict__ qkv_w, const float* __restrict__ qkv_b,
    const float* __restrict__ rb_w1, const float* __restrict__ rv_w1,
    float* __restrict__ qb, __bf16* __restrict__ kbbf, __bf16* __restrict__ vT,
    __bf16* __restrict__ Arb, __bf16* __restrict__ ArvT)
{
    int bid = blockIdx.x, tid = threadIdx.x;
    if (bid >= 576) {
        int r = bid - 576, c = tid;
        float cx = coords[r * 3 + 0], cy = coords[r * 3 + 1], cz = coords[r * 3 + 2];
        float ab = (cx * rb_w1[c * 3] + cy * rb_w1[c * 3 + 1] + cz * rb_w1[c * 3 + 2]) * LOG2E;
        float av = (cx * rv_w1[c * 3] + cy * rv_w1[c * 3 + 1] + cz * rv_w1[c * 3 + 2]) * LOG2E;
        Arb[r * DD + c] = (__bf16)ab;
        ArvT[c * RN + r] = (__bf16)av;
        return;
    }
    // qkv: M=768 (rows), N=768 (outs), K=256. 16x16 tile per wave.
    int mt = bid % 48, nb = bid / 48;
    int w = tid >> 6, l = tid & 63, lr = l & 15, lg = l >> 4;
    int m0 = mt * 16, n0 = nb * 64 + w * 16;
    const float* xr = x + (size_t)(m0 + lr) * DD;
    const float* wr = qkv_w + (size_t)(n0 + lr) * DD;
    f32x4 acc = {0.f, 0.f, 0.f, 0.f};
#pragma unroll
    for (int ks = 0; ks < 8; ++ks) {
        int c0 = ks * 32 + lg * 8;
        float4 xa = *(const float4*)(xr + c0);
        float4 xb = *(const float4*)(xr + c0 + 4);
        float4 wa = *(const float4*)(wr + c0);
        float4 wb = *(const float4*)(wr + c0 + 4);
        acc = mfma16(pack8(xa, xb), pack8(wa, wb), acc);
    }
    int col = n0 + lr;
    float bo = qkv_b[col];
    int part = col >> 8, o = col & 255;
#pragma unroll
    for (int r = 0; r < 4; ++r) {
        int m = m0 + lg * 4 + r;
        float v = acc[r] + bo;
        if (part == 0) {
            qb[(size_t)m * DD + o] = v * QSCALE;
        } else if (part == 1) {
            kbbf[(size_t)m * DD + o] = (__bf16)v;
        } else {
            int b = (m >= NN) ? 1 : 0;
            int n = m - b * NN;
            vT[(size_t)b * DD * NN + (size_t)o * NN + n] = (__bf16)v;
        }
    }
}

// ---------------- Kernel 2: fused attention, 1 i per block, 768 blocks ----------------
__global__ __launch_bounds__(512, 6) void attn_kernel(
    const float* __restrict__ rb_b1, const float* __restrict__ rb_w2,
    const float* __restrict__ rb_b2,
    const float* __restrict__ rv_b1, const float* __restrict__ rv_w2,
    const float* __restrict__ rv_b2,
    const float* __restrict__ qb, const __bf16* __restrict__ kbbf,
    const __bf16* __restrict__ vT,
    const __bf16* __restrict__ Arb, const __bf16* __restrict__ ArvT,
    float* __restrict__ out)
{
    __shared__ __align__(16) __bf16 qsbf[DD];
    __shared__ __align__(16) float Apr[DD];
    __shared__ __align__(16) float Apv[DD];
    __shared__ __align__(16) __bf16 w2bf[HH * W2_ST];
    __shared__ __align__(16) __bf16 eAbf[HH * EA_ST];
    __shared__ __align__(16) float Tl[HH * T_ST];
    __shared__ __align__(16) float basep[DD];
    __shared__ float redsum[8][HH];

    int tid = threadIdx.x;
    int bx = blockIdx.x;
    int b = bx / NN, i = bx - b * NN;
    int gi = b * NN + i;

    // ---- setup ----
    if (tid < 256) {
        qsbf[tid] = (__bf16)qb[(size_t)gi * DD + tid];
        Apr[tid] = (float)Arb[(size_t)gi * DD + tid] + rb_b1[tid] * LOG2E;
        Apv[tid] = (float)ArvT[(size_t)tid * RN + gi] + rv_b1[tid] * LOG2E;
    }
    for (int idx = tid; idx < HH * 256; idx += 512)
        w2bf[(idx >> 8) * W2_ST + (idx & 255)] = (__bf16)(-rb_w2[idx]);
    __syncthreads();

    int l = tid & 63, wv = tid >> 6;
    int lr = l & 15, lg = l >> 4;
    float rb2l = rb_b2[lr & 7] * LOG2E;

    // ---- phase 1: scores' = log2e*(rel_bias + qk/sqrt(hd)); block-diag MFMA QK ----
    {
        const __bf16* arbB = Arb + (size_t)b * NN * DD;
        const __bf16* kbB  = kbbf + (size_t)b * NN * DD;
        const __bf16* ar0 = arbB + ((wv      ) * 16 + lr) * DD;
        const __bf16* ar1 = arbB + ((wv +  8) * 16 + lr) * DD;
        const __bf16* ar2 = arbB + ((wv + 16) * 16 + lr) * DD;
        const __bf16* kr0 = kbB  + ((wv      ) * 16 + lr) * DD;
        const __bf16* kr1 = kbB  + ((wv +  8) * 16 + lr) * DD;
        const __bf16* kr2 = kbB  + ((wv + 16) * 16 + lr) * DD;
        const __bf16* wfp = &w2bf[(lr & 7) * W2_ST];
        f32x4 a0 = {0.f, 0.f, 0.f, 0.f}, a1 = a0, a2 = a0;

        // depth-1 software pipeline: prefetch ks+1 streams during ks compute
        int cP = lg * 8;
        bf16x8 nv0 = *(const bf16x8*)(ar0 + cP);
        bf16x8 nv1 = *(const bf16x8*)(ar1 + cP);
        bf16x8 nv2 = *(const bf16x8*)(ar2 + cP);
        bf16x8 nk0 = *(const bf16x8*)(kr0 + cP);
        bf16x8 nk1 = *(const bf16x8*)(kr1 + cP);
        bf16x8 nk2 = *(const bf16x8*)(kr2 + cP);
        bf16x8 nwf = *(const bf16x8*)(wfp + cP);
#pragma unroll
        for (int ks = 0; ks < 8; ++ks) {
            int c0 = ks * 32 + lg * 8;
            bf16x8 v0 = nv0, v1 = nv1, v2 = nv2;
            bf16x8 k0 = nk0, k1 = nk1, k2 = nk2, wf = nwf;
            if (ks < 7) {
                int c1 = c0 + 32;
                nv0 = *(const bf16x8*)(ar0 + c1);
                nv1 = *(const bf16x8*)(ar1 + c1);
                nv2 = *(const bf16x8*)(ar2 + c1);
                nk0 = *(const bf16x8*)(kr0 + c1);
                nk1 = *(const bf16x8*)(kr1 + c1);
                nk2 = *(const bf16x8*)(kr2 + c1);
                nwf = *(const bf16x8*)(wfp + c1);
            }
            float4 p0 = *(const float4*)&Apr[c0];
            float4 p1 = *(const float4*)&Apr[c0 + 4];
            bf16x8 qf;
            if (lr == ks) {
                qf = *(const bf16x8*)&qsbf[c0];
            } else {
#pragma unroll
                for (int e = 0; e < 8; ++e) qf[e] = (__bf16)0.f;
            }
            a0 = mfma16(hid8(v0, p0, p1), wf, a0);
            a1 = mfma16(hid8(v1, p0, p1), wf, a1);
            a2 = mfma16(hid8(v2, p0, p1), wf, a2);
            a0 = mfma16(k0, qf, a0);
            a1 = mfma16(k1, qf, a1);
            a2 = mfma16(k2, qf, a2);
        }
        // e = exp2(score' + rb_b2'); Z partials; e (bf16) -> LDS A-frag rows
        float z = 0.f;
#define FINTILE(ACC, T) { \
            float e0 = __builtin_amdgcn_exp2f(ACC[0] + rb2l); \
            float e1 = __builtin_amdgcn_exp2f(ACC[1] + rb2l); \
            float e2 = __builtin_amdgcn_exp2f(ACC[2] + rb2l); \
            float e3 = __builtin_amdgcn_exp2f(ACC[3] + rb2l); \
            if (lr < 8) { \
                bf16x4 ev; \
                ev[0] = (__bf16)e0; ev[1] = (__bf16)e1; \
                ev[2] = (__bf16)e2; ev[3] = (__bf16)e3; \
                *(bf16x4*)&eAbf[lr * EA_ST + ((T) * 8 + wv) * 16 + lg * 4] = ev; \
            } \
            float zs = e0 + e1 + e2 + e3; \
            zs += __shfl_xor(zs, 16); \
            zs += __shfl_xor(zs, 32); \
            z += zs; }
        FINTILE(a0, 0)
        FINTILE(a1, 1)
        FINTILE(a2, 2)
#undef FINTILE
        if (lg == 0 && lr < 8) redsum[wv][lr] = z;
    }
    __syncthreads();

    // ---- phase 2: T[h][c] (hid') and base[h][d] (vT) via MFMA, K = j ----
    {
        int c0 = wv * 16 + lr, c1 = c0 + 128;
        float ap0 = Apv[c0], ap1 = Apv[c1];
        const __bf16* vr0 = ArvT + (size_t)c0 * RN + b * NN;
        const __bf16* vr1 = ArvT + (size_t)c1 * RN + b * NN;
        const __bf16* tv0 = vT + (size_t)b * DD * NN + (size_t)c0 * NN;
        const __bf16* tv1 = vT + (size_t)b * DD * NN + (size_t)c1 * NN;
        const __bf16* efp = &eAbf[(lr & 7) * EA_ST];
        f32x4 T0 = {0.f, 0.f, 0.f, 0.f}, T1 = T0, B0 = T0, B1 = T0;

        int jP = lg * 8;
        bf16x8 nef = *(const bf16x8*)(efp + jP);
        bf16x8 na0 = *(const bf16x8*)(vr0 + jP);
        bf16x8 na1 = *(const bf16x8*)(vr1 + jP);
        bf16x8 nw0 = *(const bf16x8*)(tv0 + jP);
        bf16x8 nw1 = *(const bf16x8*)(tv1 + jP);
#pragma unroll
        for (int ks = 0; ks < 12; ++ks) {
            bf16x8 ef = nef, av0 = na0, av1 = na1, w0 = nw0, w1 = nw1;
            if (ks < 11) {
                int j1 = (ks + 1) * 32 + lg * 8;
                nef = *(const bf16x8*)(efp + j1);
                na0 = *(const bf16x8*)(vr0 + j1);
                na1 = *(const bf16x8*)(vr1 + j1);
                nw0 = *(const bf16x8*)(tv0 + j1);
                nw1 = *(const bf16x8*)(tv1 + j1);
            }
            T0 = mfma16(ef, hid8s(av0, ap0), T0);
            T1 = mfma16(ef, hid8s(av1, ap1), T1);
            B0 = mfma16(ef, w0, B0);
            B1 = mfma16(ef, w1, B1);
        }
        if (lg < 2) {
#pragma unroll
            for (int r = 0; r < 4; ++r) {
                int h = lg * 4 + r;
                Tl[h * T_ST + c0] = T0[r] * NLN2;
                Tl[h * T_ST + c1] = T1[r] * NLN2;
            }
        }
        // base extraction: D[row=h][col=c]; needed h = c>>5
        int h0 = wv >> 1, h1 = 4 + (wv >> 1);
        int dcol = (wv & 1) * 16 + lr;
        if (lg == (h0 >> 2)) {
            int r = h0 & 3;
            basep[h0 * 32 + dcol] = (r == 0) ? B0[0] : (r == 1) ? B0[1] : (r == 2) ? B0[2] : B0[3];
        }
        if (lg == (h1 >> 2)) {
            int r = h1 & 3;
            basep[h1 * 32 + dcol] = (r == 0) ? B1[0] : (r == 1) ? B1[1] : (r == 2) ? B1[2] : B1[3];
        }
    }
    __syncthreads();

    // ---- epilogue: rc = T @ rv_w2^T; out = (rc + base)/Z + rv_b2 ----
    if (tid < 256) {
        int o = tid, h = o >> 5;
        float z = 0.f;
#pragma unroll
        for (int w = 0; w < 8; ++w) z += redsum[w][h];
        const float4* w2p = (const float4*)(rv_w2 + (size_t)o * DD);
        float a = 0.f;
#pragma unroll 4
        for (int cc = 0; cc < 64; ++cc) {
            float4 wv4 = w2p[cc];
            float4 tv = *(const float4*)&Tl[h * T_ST + cc * 4];
            a += wv4.x * tv.x + wv4.y * tv.y + wv4.z * tv.z + wv4.w * tv.w;
        }
        out[(size_t)gi * DD + o] = (a + basep[o]) * __builtin_amdgcn_rcpf(z) + rv_b2[o];
    }
}

extern "C" void kernel_launch(void* const* d_in, const int* in_sizes, int n_in,
                              void* d_out, int out_size, void* d_ws, size_t ws_size,
                              hipStream_t stream) {
    const float* x      = (const float*)d_in[0];
    const float* coords = (const float*)d_in[1];
    const float* qkv_w  = (const float*)d_in[2];
    const float* qkv_b  = (const float*)d_in[3];
    const float* rb_w1  = (const float*)d_in[4];
    const float* rb_b1  = (const float*)d_in[5];
    const float* rb_w2  = (const float*)d_in[6];
    const float* rb_b2  = (const float*)d_in[7];
    const float* rv_w1  = (const float*)d_in[8];
    const float* rv_b1  = (const float*)d_in[9];
    const float* rv_w2  = (const float*)d_in[10];
    const float* rv_b2  = (const float*)d_in[11];
    float* out = (float*)d_out;

    float* ws = (float*)d_ws;
    const int PER = RN * DD;               // 196608
    float* qb = ws;                        // f32
    __bf16* bfb  = (__bf16*)(ws + PER);
    __bf16* kbbf = bfb;                    // PER bf16
    __bf16* vTb  = bfb + PER;              // PER bf16
    __bf16* Arb  = bfb + 2 * PER;          // PER bf16
    __bf16* ArvT = bfb + 3 * PER;          // PER bf16

    prep_kernel<<<576 + RN, 256, 0, stream>>>(x, coords, qkv_w, qkv_b,
                                              rb_w1, rv_w1, qb, kbbf, vTb, Arb, ArvT);
    attn_kernel<<<RN, 512, 0, stream>>>(
        rb_b1, rb_w2, rb_b2, rv_b1, rv_w2, rv_b2,
        qb, kbbf, vTb, Arb, ArvT, out);
}

// Round 6
// 108.883 us; speedup vs baseline: 1.2006x; 1.2006x over previous
//
#include <hip/hip_runtime.h>
#include <math.h>

#define BB 2
#define NN 384
#define DD 256
#define HH 8
#define RN (BB * NN)   // 768
#define INV_SQRT_HD 0.17677669529663687f   // 1/sqrt(32)
#define LOG2E 1.4426950408889634f
#define NLN2 -0.6931471805599453f
#define QSCALE (INV_SQRT_HD * LOG2E)

#define W2_ST 264   // bf16 stride, rb_w2 rows
#define EA_ST 392   // bf16 stride, e A-frag rows
#define T_ST  264   // f32 stride, T rows

typedef float f32x4 __attribute__((ext_vector_type(4)));
typedef __bf16 bf16x8 __attribute__((ext_vector_type(8)));
typedef __bf16 bf16x4 __attribute__((ext_vector_type(4)));

__device__ __forceinline__ f32x4 mfma16(bf16x8 a, bf16x8 b, f32x4 c) {
    return __builtin_amdgcn_mfma_f32_16x16x32_bf16(a, b, c, 0, 0, 0);
}

// d = av' - ap'  where primes are pre-scaled by log2e, i.e. d = -x*log2e.
// returns -log2e * silu(x); downstream folds: phase1 w2bf = -rb_w2 (since
// -ln2*log2e = -1 and scores want a log2e scale); phase2 Tl *= -ln2.
__device__ __forceinline__ float hidp(float d) {
    float e = __builtin_amdgcn_exp2f(d);              // = exp(-x)
    return d * __builtin_amdgcn_rcpf(1.0f + e);       // = -log2e * x * sigmoid(x)
}
__device__ __forceinline__ bf16x8 hid8(bf16x8 av, float4 a0, float4 a1) {
    bf16x8 r;
    r[0] = (__bf16)hidp((float)av[0] - a0.x);
    r[1] = (__bf16)hidp((float)av[1] - a0.y);
    r[2] = (__bf16)hidp((float)av[2] - a0.z);
    r[3] = (__bf16)hidp((float)av[3] - a0.w);
    r[4] = (__bf16)hidp((float)av[4] - a1.x);
    r[5] = (__bf16)hidp((float)av[5] - a1.y);
    r[6] = (__bf16)hidp((float)av[6] - a1.z);
    r[7] = (__bf16)hidp((float)av[7] - a1.w);
    return r;
}
__device__ __forceinline__ bf16x8 hid8s(bf16x8 av, float a) {
    bf16x8 r;
#pragma unroll
    for (int q = 0; q < 8; ++q) r[q] = (__bf16)hidp((float)av[q] - a);
    return r;
}
__device__ __forceinline__ bf16x8 pack8(float4 a, float4 b) {
    bf16x8 r;
    r[0] = (__bf16)a.x; r[1] = (__bf16)a.y; r[2] = (__bf16)a.z; r[3] = (__bf16)a.w;
    r[4] = (__bf16)b.x; r[5] = (__bf16)b.y; r[6] = (__bf16)b.z; r[7] = (__bf16)b.w;
    return r;
}

// ---------------- Kernel 1: fused prep ----------------
// blocks [0,576): qkv via MFMA.  blocks [576,1344): A-array precompute.
// q: f32 [768][256] pre-scaled by log2e/sqrt(32); k: bf16 [768][256];
// vT: bf16 [b][256(hd)][384(n)]
// Arb[r][c] = (coords_r . rb_w1_c)*log2e   (bf16, [768][256])
// ArvT[c][r] = (coords_r . rv_w1_c)*log2e  (bf16, [256][768])
__global__ __launch_bounds__(256) void prep_kernel(
    const float* __restrict__ x, const float* __restrict__ coords,
    const float* __restrict__ qkv_w, const float* __restrict__ qkv_b,
    const float* __restrict__ rb_w1, const float* __restrict__ rv_w1,
    float* __restrict__ qb, __bf16* __restrict__ kbbf, __bf16* __restrict__ vT,
    __bf16* __restrict__ Arb, __bf16* __restrict__ ArvT)
{
    int bid = blockIdx.x, tid = threadIdx.x;
    if (bid >= 576) {
        int r = bid - 576, c = tid;
        float cx = coords[r * 3 + 0], cy = coords[r * 3 + 1], cz = coords[r * 3 + 2];
        float ab = (cx * rb_w1[c * 3] + cy * rb_w1[c * 3 + 1] + cz * rb_w1[c * 3 + 2]) * LOG2E;
        float av = (cx * rv_w1[c * 3] + cy * rv_w1[c * 3 + 1] + cz * rv_w1[c * 3 + 2]) * LOG2E;
        Arb[r * DD + c] = (__bf16)ab;
        ArvT[c * RN + r] = (__bf16)av;
        return;
    }
    // qkv: M=768 (rows), N=768 (outs), K=256. 16x16 tile per wave.
    int mt = bid % 48, nb = bid / 48;
    int w = tid >> 6, l = tid & 63, lr = l & 15, lg = l >> 4;
    int m0 = mt * 16, n0 = nb * 64 + w * 16;
    const float* xr = x + (size_t)(m0 + lr) * DD;
    const float* wr = qkv_w + (size_t)(n0 + lr) * DD;
    f32x4 acc = {0.f, 0.f, 0.f, 0.f};
#pragma unroll
    for (int ks = 0; ks < 8; ++ks) {
        int c0 = ks * 32 + lg * 8;
        float4 xa = *(const float4*)(xr + c0);
        float4 xb = *(const float4*)(xr + c0 + 4);
        float4 wa = *(const float4*)(wr + c0);
        float4 wb = *(const float4*)(wr + c0 + 4);
        acc = mfma16(pack8(xa, xb), pack8(wa, wb), acc);
    }
    int col = n0 + lr;
    float bo = qkv_b[col];
    int part = col >> 8, o = col & 255;
#pragma unroll
    for (int r = 0; r < 4; ++r) {
        int m = m0 + lg * 4 + r;
        float v = acc[r] + bo;
        if (part == 0) {
            qb[(size_t)m * DD + o] = v * QSCALE;
        } else if (part == 1) {
            kbbf[(size_t)m * DD + o] = (__bf16)v;
        } else {
            int b = (m >= NN) ? 1 : 0;
            int n = m - b * NN;
            vT[(size_t)b * DD * NN + (size_t)o * NN + n] = (__bf16)v;
        }
    }
}

// ---------------- Kernel 2: fused attention, 1 i per block, 768 blocks ----------------
// launch_bounds(512,4): 128-VGPR cap so the prefetch pipeline stays in registers.
__global__ __launch_bounds__(512, 4) void attn_kernel(
    const float* __restrict__ rb_b1, const float* __restrict__ rb_w2,
    const float* __restrict__ rb_b2,
    const float* __restrict__ rv_b1, const float* __restrict__ rv_w2,
    const float* __restrict__ rv_b2,
    const float* __restrict__ qb, const __bf16* __restrict__ kbbf,
    const __bf16* __restrict__ vT,
    const __bf16* __restrict__ Arb, const __bf16* __restrict__ ArvT,
    float* __restrict__ out)
{
    __shared__ __align__(16) __bf16 qsbf[DD];
    __shared__ __align__(16) float Apr[DD];
    __shared__ __align__(16) float Apv[DD];
    __shared__ __align__(16) __bf16 w2bf[HH * W2_ST];
    __shared__ __align__(16) __bf16 eAbf[HH * EA_ST];
    __shared__ __align__(16) float Tl[HH * T_ST];
    __shared__ __align__(16) float basep[DD];
    __shared__ float redsum[8][HH];

    int tid = threadIdx.x;
    int bx = blockIdx.x;
    int b = bx / NN, i = bx - b * NN;
    int gi = b * NN + i;

    // ---- setup ----
    if (tid < 256) {
        qsbf[tid] = (__bf16)qb[(size_t)gi * DD + tid];
        Apr[tid] = (float)Arb[(size_t)gi * DD + tid] + rb_b1[tid] * LOG2E;
        Apv[tid] = (float)ArvT[(size_t)tid * RN + gi] + rv_b1[tid] * LOG2E;
    }
    for (int idx = tid; idx < HH * 256; idx += 512)
        w2bf[(idx >> 8) * W2_ST + (idx & 255)] = (__bf16)(-rb_w2[idx]);
    __syncthreads();

    int l = tid & 63, wv = tid >> 6;
    int lr = l & 15, lg = l >> 4;
    float rb2l = rb_b2[lr & 7] * LOG2E;

    // ---- phase 1: scores' = log2e*(rel_bias + qk/sqrt(hd)); block-diag MFMA QK ----
    {
        const __bf16* arbB = Arb + (size_t)b * NN * DD;
        const __bf16* kbB  = kbbf + (size_t)b * NN * DD;
        const __bf16* ar0 = arbB + ((wv      ) * 16 + lr) * DD;
        const __bf16* ar1 = arbB + ((wv +  8) * 16 + lr) * DD;
        const __bf16* ar2 = arbB + ((wv + 16) * 16 + lr) * DD;
        const __bf16* kr0 = kbB  + ((wv      ) * 16 + lr) * DD;
        const __bf16* kr1 = kbB  + ((wv +  8) * 16 + lr) * DD;
        const __bf16* kr2 = kbB  + ((wv + 16) * 16 + lr) * DD;
        const __bf16* wfp = &w2bf[(lr & 7) * W2_ST];
        f32x4 a0 = {0.f, 0.f, 0.f, 0.f}, a1 = a0, a2 = a0;

        // depth-1 software pipeline on the 6 GLOBAL streams only (24 VGPRs);
        // wf (LDS) is read just-in-time.
        int cP = lg * 8;
        bf16x8 nv0 = *(const bf16x8*)(ar0 + cP);
        bf16x8 nv1 = *(const bf16x8*)(ar1 + cP);
        bf16x8 nv2 = *(const bf16x8*)(ar2 + cP);
        bf16x8 nk0 = *(const bf16x8*)(kr0 + cP);
        bf16x8 nk1 = *(const bf16x8*)(kr1 + cP);
        bf16x8 nk2 = *(const bf16x8*)(kr2 + cP);
#pragma unroll
        for (int ks = 0; ks < 8; ++ks) {
            int c0 = ks * 32 + lg * 8;
            bf16x8 v0 = nv0, v1 = nv1, v2 = nv2;
            bf16x8 k0 = nk0, k1 = nk1, k2 = nk2;
            if (ks < 7) {
                int c1 = c0 + 32;
                nv0 = *(const bf16x8*)(ar0 + c1);
                nv1 = *(const bf16x8*)(ar1 + c1);
                nv2 = *(const bf16x8*)(ar2 + c1);
                nk0 = *(const bf16x8*)(kr0 + c1);
                nk1 = *(const bf16x8*)(kr1 + c1);
                nk2 = *(const bf16x8*)(kr2 + c1);
            }
            bf16x8 wf = *(const bf16x8*)(wfp + c0);
            float4 p0 = *(const float4*)&Apr[c0];
            float4 p1 = *(const float4*)&Apr[c0 + 4];
            bf16x8 qf;
            if (lr == ks) {
                qf = *(const bf16x8*)&qsbf[c0];
            } else {
#pragma unroll
                for (int e = 0; e < 8; ++e) qf[e] = (__bf16)0.f;
            }
            a0 = mfma16(hid8(v0, p0, p1), wf, a0);
            a1 = mfma16(hid8(v1, p0, p1), wf, a1);
            a2 = mfma16(hid8(v2, p0, p1), wf, a2);
            a0 = mfma16(k0, qf, a0);
            a1 = mfma16(k1, qf, a1);
            a2 = mfma16(k2, qf, a2);
        }
        // e = exp2(score' + rb_b2'); Z partials; e (bf16) -> LDS A-frag rows
        float z = 0.f;
#define FINTILE(ACC, T) { \
            float e0 = __builtin_amdgcn_exp2f(ACC[0] + rb2l); \
            float e1 = __builtin_amdgcn_exp2f(ACC[1] + rb2l); \
            float e2 = __builtin_amdgcn_exp2f(ACC[2] + rb2l); \
            float e3 = __builtin_amdgcn_exp2f(ACC[3] + rb2l); \
            if (lr < 8) { \
                bf16x4 ev; \
                ev[0] = (__bf16)e0; ev[1] = (__bf16)e1; \
                ev[2] = (__bf16)e2; ev[3] = (__bf16)e3; \
                *(bf16x4*)&eAbf[lr * EA_ST + ((T) * 8 + wv) * 16 + lg * 4] = ev; \
            } \
            float zs = e0 + e1 + e2 + e3; \
            zs += __shfl_xor(zs, 16); \
            zs += __shfl_xor(zs, 32); \
            z += zs; }
        FINTILE(a0, 0)
        FINTILE(a1, 1)
        FINTILE(a2, 2)
#undef FINTILE
        if (lg == 0 && lr < 8) redsum[wv][lr] = z;
    }
    __syncthreads();

    // ---- phase 2: T[h][c] (hid') and base[h][d] (vT) via MFMA, K = j ----
    {
        int c0 = wv * 16 + lr, c1 = c0 + 128;
        float ap0 = Apv[c0], ap1 = Apv[c1];
        const __bf16* vr0 = ArvT + (size_t)c0 * RN + b * NN;
        const __bf16* vr1 = ArvT + (size_t)c1 * RN + b * NN;
        const __bf16* tv0 = vT + (size_t)b * DD * NN + (size_t)c0 * NN;
        const __bf16* tv1 = vT + (size_t)b * DD * NN + (size_t)c1 * NN;
        const __bf16* efp = &eAbf[(lr & 7) * EA_ST];
        f32x4 T0 = {0.f, 0.f, 0.f, 0.f}, T1 = T0, B0 = T0, B1 = T0;

        // depth-1 pipeline on the 4 GLOBAL streams (16 VGPRs); ef (LDS) JIT.
        int jP = lg * 8;
        bf16x8 na0 = *(const bf16x8*)(vr0 + jP);
        bf16x8 na1 = *(const bf16x8*)(vr1 + jP);
        bf16x8 nw0 = *(const bf16x8*)(tv0 + jP);
        bf16x8 nw1 = *(const bf16x8*)(tv1 + jP);
#pragma unroll
        for (int ks = 0; ks < 12; ++ks) {
            bf16x8 av0 = na0, av1 = na1, w0 = nw0, w1 = nw1;
            if (ks < 11) {
                int j1 = (ks + 1) * 32 + lg * 8;
                na0 = *(const bf16x8*)(vr0 + j1);
                na1 = *(const bf16x8*)(vr1 + j1);
                nw0 = *(const bf16x8*)(tv0 + j1);
                nw1 = *(const bf16x8*)(tv1 + j1);
            }
            bf16x8 ef = *(const bf16x8*)(efp + ks * 32 + lg * 8);
            T0 = mfma16(ef, hid8s(av0, ap0), T0);
            T1 = mfma16(ef, hid8s(av1, ap1), T1);
            B0 = mfma16(ef, w0, B0);
            B1 = mfma16(ef, w1, B1);
        }
        if (lg < 2) {
#pragma unroll
            for (int r = 0; r < 4; ++r) {
                int h = lg * 4 + r;
                Tl[h * T_ST + c0] = T0[r] * NLN2;
                Tl[h * T_ST + c1] = T1[r] * NLN2;
            }
        }
        // base extraction: D[row=h][col=c]; needed h = c>>5
        int h0 = wv >> 1, h1 = 4 + (wv >> 1);
        int dcol = (wv & 1) * 16 + lr;
        if (lg == (h0 >> 2)) {
            int r = h0 & 3;
            basep[h0 * 32 + dcol] = (r == 0) ? B0[0] : (r == 1) ? B0[1] : (r == 2) ? B0[2] : B0[3];
        }
        if (lg == (h1 >> 2)) {
            int r = h1 & 3;
            basep[h1 * 32 + dcol] = (r == 0) ? B1[0] : (r == 1) ? B1[1] : (r == 2) ? B1[2] : B1[3];
        }
    }
    __syncthreads();

    // ---- epilogue: rc = T @ rv_w2^T; out = (rc + base)/Z + rv_b2 ----
    if (tid < 256) {
        int o = tid, h = o >> 5;
        float z = 0.f;
#pragma unroll
        for (int w = 0; w < 8; ++w) z += redsum[w][h];
        const float4* w2p = (const float4*)(rv_w2 + (size_t)o * DD);
        float a = 0.f;
#pragma unroll 4
        for (int cc = 0; cc < 64; ++cc) {
            float4 wv4 = w2p[cc];
            float4 tv = *(const float4*)&Tl[h * T_ST + cc * 4];
            a += wv4.x * tv.x + wv4.y * tv.y + wv4.z * tv.z + wv4.w * tv.w;
        }
        out[(size_t)gi * DD + o] = (a + basep[o]) * __builtin_amdgcn_rcpf(z) + rv_b2[o];
    }
}

extern "C" void kernel_launch(void* const* d_in, const int* in_sizes, int n_in,
                              void* d_out, int out_size, void* d_ws, size_t ws_size,
                              hipStream_t stream) {
    const float* x      = (const float*)d_in[0];
    const float* coords = (const float*)d_in[1];
    const float* qkv_w  = (const float*)d_in[2];
    const float* qkv_b  = (const float*)d_in[3];
    const float* rb_w1  = (const float*)d_in[4];
    const float* rb_b1  = (const float*)d_in[5];
    const float* rb_w2  = (const float*)d_in[6];
    const float* rb_b2  = (const float*)d_in[7];
    const float* rv_w1  = (const float*)d_in[8];
    const float* rv_b1  = (const float*)d_in[9];
    const float* rv_w2  = (const float*)d_in[10];
    const float* rv_b2  = (const float*)d_in[11];
    float* out = (float*)d_out;

    float* ws = (float*)d_ws;
    const int PER = RN * DD;               // 196608
    float* qb = ws;                        // f32
    __bf16* bfb  = (__bf16*)(ws + PER);
    __bf16* kbbf = bfb;                    // PER bf16
    __bf16* vTb  = bfb + PER;              // PER bf16
    __bf16* Arb  = bfb + 2 * PER;          // PER bf16
    __bf16* ArvT = bfb + 3 * PER;          // PER bf16

    prep_kernel<<<576 + RN, 256, 0, stream>>>(x, coords, qkv_w, qkv_b,
                                              rb_w1, rv_w1, qb, kbbf, vTb, Arb, ArvT);
    attn_kernel<<<RN, 512, 0, stream>>>(
        rb_b1, rb_w2, rb_b2, rv_b1, rv_w2, rv_b2,
        qb, kbbf, vTb, Arb, ArvT, out);
}